// Round 1
// baseline (9363.732 us; speedup 1.0000x reference)
//
#include <hip/hip_runtime.h>
#include <hip/hip_bf16.h>
#include <math.h>

#define NBATCH 8192   // N*B fused batch
#define BDIM 64
#define NDIM 128
#define TSRC 48
#define TTGT 12
#define CDIM 3
#define HDIM 128
#define GRU_ROWS 16

__device__ __forceinline__ float sigmoidf_(float x){ return 1.0f/(1.0f+__expf(-x)); }
__device__ __forceinline__ float to_f(float x){ return x; }
__device__ __forceinline__ float to_f(__hip_bfloat16 x){ return __bfloat162float(x); }
__device__ __forceinline__ void st_v(float* d, float v){ *d = v; }
__device__ __forceinline__ void st_v(__hip_bfloat16* d, float v){ *d = __float2bfloat16(v); }

// xs[t][nb][c] = flow_x[b][n][t][c], nb = n*B + b
__global__ __launch_bounds__(256) void pack_xs_kernel(const float* __restrict__ fx,
                                                      float* __restrict__ xs){
  int idx = blockIdx.x*256 + threadIdx.x;
  const int total = TSRC*NBATCH*CDIM;
  if (idx >= total) return;
  int c = idx % CDIM; int r = idx / CDIM;
  int nb = r % NBATCH; int t = r / NBATCH;
  int n = nb >> 6, b = nb & 63;
  xs[idx] = fx[(((size_t)(b*NDIM) + n)*TSRC + t)*CDIM + c];
}

// One GRU step for 16 rows/block. x = [xa | xb] staged to LDS. h updated in place.
__global__ __launch_bounds__(256) void gru_step_kernel(
    const float* __restrict__ xa, int Ka,
    const float* __restrict__ xb, int Kb,
    float* __restrict__ h,
    const float* __restrict__ w_ih, const float* __restrict__ w_hh,
    const float* __restrict__ b_ih, const float* __restrict__ b_hh,
    __hip_bfloat16* __restrict__ y_store)
{
  __shared__ float hs[GRU_ROWS][HDIM];
  __shared__ float xsm[GRU_ROWS][132];
  const int K = Ka + Kb;
  const int row0 = blockIdx.x * GRU_ROWS;
  const int tid = threadIdx.x;
  for (int e = tid; e < GRU_ROWS*HDIM; e += 256)
    hs[e>>7][e&127] = h[(size_t)(row0 + (e>>7))*HDIM + (e&127)];
  for (int e = tid; e < GRU_ROWS*K; e += 256) {
    int r = e / K, c = e - r*K;
    xsm[r][c] = (c < Ka) ? xa[(size_t)(row0+r)*Ka + c] : xb[(size_t)(row0+r)*Kb + (c - Ka)];
  }
  __syncthreads();
  const int j = tid & 127, rh = tid >> 7;
  float accR[8], accZ[8], accNi[8], accNh[8];
  #pragma unroll
  for (int i=0;i<8;i++){accR[i]=0.f;accZ[i]=0.f;accNi[i]=0.f;accNh[i]=0.f;}
  // gh = h @ w_hh.T
  {
    const float* wr = w_hh + (size_t)j*HDIM;
    const float* wz = w_hh + (size_t)(j+HDIM)*HDIM;
    const float* wn = w_hh + (size_t)(j+2*HDIM)*HDIM;
    for (int k=0;k<HDIM;k+=4){
      float4 a4 = *(const float4*)(wr+k);
      float4 b4 = *(const float4*)(wz+k);
      float4 c4 = *(const float4*)(wn+k);
      #pragma unroll
      for (int i=0;i<8;i++){
        int r = rh + 2*i;
        float4 hv = *(const float4*)(&hs[r][k]);
        accR[i]  += a4.x*hv.x + a4.y*hv.y + a4.z*hv.z + a4.w*hv.w;
        accZ[i]  += b4.x*hv.x + b4.y*hv.y + b4.z*hv.z + b4.w*hv.w;
        accNh[i] += c4.x*hv.x + c4.y*hv.y + c4.z*hv.z + c4.w*hv.w;
      }
    }
  }
  // gi = x @ w_ih.T
  {
    const float* wr = w_ih + (size_t)j*K;
    const float* wz = w_ih + (size_t)(j+HDIM)*K;
    const float* wn = w_ih + (size_t)(j+2*HDIM)*K;
    if ((K & 3) == 0) {
      for (int k=0;k<K;k+=4){
        float4 a4 = *(const float4*)(wr+k);
        float4 b4 = *(const float4*)(wz+k);
        float4 c4 = *(const float4*)(wn+k);
        #pragma unroll
        for (int i=0;i<8;i++){
          int r = rh + 2*i;
          float4 xv = *(const float4*)(&xsm[r][k]);
          accR[i]  += a4.x*xv.x + a4.y*xv.y + a4.z*xv.z + a4.w*xv.w;
          accZ[i]  += b4.x*xv.x + b4.y*xv.y + b4.z*xv.z + b4.w*xv.w;
          accNi[i] += c4.x*xv.x + c4.y*xv.y + c4.z*xv.z + c4.w*xv.w;
        }
      }
    } else {
      for (int k=0;k<K;k++){
        float wa=wr[k], wb=wz[k], wc=wn[k];
        #pragma unroll
        for (int i=0;i<8;i++){
          int r=rh+2*i; float xv=xsm[r][k];
          accR[i]+=wa*xv; accZ[i]+=wb*xv; accNi[i]+=wc*xv;
        }
      }
    }
  }
  float bri=b_ih[j], bzi=b_ih[HDIM+j], bni=b_ih[2*HDIM+j];
  float brh=b_hh[j], bzh=b_hh[HDIM+j], bnh=b_hh[2*HDIM+j];
  #pragma unroll
  for (int i=0;i<8;i++){
    int r = rh + 2*i;
    float rr = sigmoidf_(accR[i] + bri + brh);
    float zz = sigmoidf_(accZ[i] + bzi + bzh);
    float nn = tanhf(accNi[i] + bni + rr*(accNh[i] + bnh));
    float hv = hs[r][j];
    float hn = (1.0f - zz)*nn + zz*hv;
    size_t gidx = (size_t)(row0 + r)*HDIM + j;
    h[gidx] = hn;
    if (y_store) y_store[gidx] = __float2bfloat16(hn);
  }
}

// C[m,j] = act( sum_k A[m,k] * W[j*wstride + woff + k] + bias[j] ), j<128, k<128
template<typename AT, typename CT, int ACT>
__global__ __launch_bounds__(256) void gemm128_kernel(
  const AT* __restrict__ A, const float* __restrict__ W, int wstride, int woff,
  const float* __restrict__ bias, CT* __restrict__ C, int M)
{
  __shared__ float As[16][HDIM];
  const int row0 = blockIdx.x*16;
  const int tid = threadIdx.x;
  for (int e=tid; e<16*HDIM; e+=256)
    As[e>>7][e&127] = to_f(A[(size_t)(row0+(e>>7))*HDIM + (e&127)]);
  __syncthreads();
  const int j = tid & 127, rh = tid >> 7;
  float acc[8];
  #pragma unroll
  for (int i=0;i<8;i++) acc[i]=0.f;
  const float* wrow = W + (size_t)j*wstride + woff;
  for (int k=0;k<HDIM;k+=4){
    float4 w4 = *(const float4*)(wrow + k);
    #pragma unroll
    for (int i=0;i<8;i++){
      int r = rh + 2*i;
      float4 av = *(const float4*)(&As[r][k]);
      acc[i] += w4.x*av.x + w4.y*av.y + w4.z*av.z + w4.w*av.w;
    }
  }
  float bb = bias ? bias[j] : 0.0f;
  #pragma unroll
  for (int i=0;i<8;i++){
    float v = acc[i] + bb;
    if (ACT==1) v = tanhf(v);
    st_v(&C[(size_t)(row0 + rh + 2*i)*HDIM + j], v);
  }
}

// Per-nb attention: scores over TS, softmax, context. One wave per nb.
__global__ __launch_bounds__(64) void attn_kernel(
  const __hip_bfloat16* __restrict__ p, const float* __restrict__ q,
  const __hip_bfloat16* __restrict__ en, const float* __restrict__ v_w,
  float* __restrict__ ctx)
{
  const int nb = blockIdx.x; const int lane = threadIdx.x;
  __shared__ float qs[128], vs[128], sc[TSRC];
  qs[lane] = q[(size_t)nb*HDIM + lane]; qs[lane+64] = q[(size_t)nb*HDIM + lane + 64];
  vs[lane] = v_w[lane]; vs[lane+64] = v_w[lane+64];
  __syncthreads();
  for (int t=0;t<TSRC;t++){
    const __hip_bfloat16* pr = p + ((size_t)t*NBATCH + nb)*HDIM;
    float s = vs[lane]*tanhf(__bfloat162float(pr[lane]) + qs[lane])
            + vs[lane+64]*tanhf(__bfloat162float(pr[lane+64]) + qs[lane+64]);
    #pragma unroll
    for (int off=32; off>=1; off>>=1) s += __shfl_xor(s, off, 64);
    if (lane==0) sc[t] = s;
  }
  __syncthreads();
  float m = -1e30f;
  for (int t=0;t<TSRC;t++) m = fmaxf(m, sc[t]);
  if (lane < TSRC) sc[lane] = __expf(sc[lane] - m);
  __syncthreads();
  float den = 0.f;
  for (int t=0;t<TSRC;t++) den += sc[t];
  float rden = 1.0f/den;
  float c0=0.f, c1=0.f;
  for (int t=0;t<TSRC;t++){
    const __hip_bfloat16* er = en + ((size_t)t*NBATCH + nb)*HDIM;
    float a = sc[t]*rden;
    c0 += a*__bfloat162float(er[lane]);
    c1 += a*__bfloat162float(er[lane+64]);
  }
  ctx[(size_t)nb*HDIM + lane] = c0; ctx[(size_t)nb*HDIM + lane + 64] = c1;
}

// out = [h1,h1,dec_in] @ fc_w.T + fc_b ; writes pred + next dec_in
__global__ __launch_bounds__(256) void fc_kernel(
  const float* __restrict__ h1, const float* __restrict__ din,
  const float* __restrict__ fc_w, const float* __restrict__ fc_b,
  float* __restrict__ pred, float* __restrict__ din_next, int t)
{
  int nb = blockIdx.x*256 + threadIdx.x;
  if (nb >= NBATCH) return;
  float d0 = din[nb*3], d1 = din[nb*3+1], d2 = din[nb*3+2];
  float o0 = fc_b[0], o1 = fc_b[1], o2 = fc_b[2];
  const float* h1r = h1 + (size_t)nb*HDIM;
  const int WS = 2*HDIM + CDIM; // 259
  for (int hh=0; hh<HDIM; hh++){
    float hv = h1r[hh];
    o0 += (fc_w[0*WS + hh] + fc_w[0*WS + HDIM + hh]) * hv;
    o1 += (fc_w[1*WS + hh] + fc_w[1*WS + HDIM + hh]) * hv;
    o2 += (fc_w[2*WS + hh] + fc_w[2*WS + HDIM + hh]) * hv;
  }
  o0 += fc_w[0*WS+256]*d0 + fc_w[0*WS+257]*d1 + fc_w[0*WS+258]*d2;
  o1 += fc_w[1*WS+256]*d0 + fc_w[1*WS+257]*d1 + fc_w[1*WS+258]*d2;
  o2 += fc_w[2*WS+256]*d0 + fc_w[2*WS+257]*d1 + fc_w[2*WS+258]*d2;
  int n = nb >> 6, b = nb & 63;
  float* pr = pred + (((size_t)(b*NDIM + n)*TTGT + t)*CDIM);
  pr[0]=o0; pr[1]=o1; pr[2]=o2;
  din_next[nb*3+0]=o0; din_next[nb*3+1]=o1; din_next[nb*3+2]=o2;
}

extern "C" void kernel_launch(void* const* d_in, const int* in_sizes, int n_in,
                              void* d_out, int out_size, void* d_ws, size_t ws_size,
                              hipStream_t stream)
{
  const float* flow_x   = (const float*)d_in[0];
  const float* flow_y   = (const float*)d_in[1];
  const float* enc_w_ih0= (const float*)d_in[2];
  const float* enc_w_ih1= (const float*)d_in[3];
  const float* enc_w_hh = (const float*)d_in[4];
  const float* enc_b_ih = (const float*)d_in[5];
  const float* enc_b_hh = (const float*)d_in[6];
  const float* enc_hid_w= (const float*)d_in[7];
  const float* enc_hid_b= (const float*)d_in[8];
  const float* dec_w_ih0= (const float*)d_in[9];
  const float* dec_w_ih1= (const float*)d_in[10];
  const float* dec_w_hh = (const float*)d_in[11];
  const float* dec_b_ih = (const float*)d_in[12];
  const float* dec_b_hh = (const float*)d_in[13];
  const float* attn_w   = (const float*)d_in[14];
  const float* attn_b   = (const float*)d_in[15];
  const float* v_w      = (const float*)d_in[16];
  const float* fc_w     = (const float*)d_in[17];
  const float* fc_b     = (const float*)d_in[18];

  float* out_pred = (float*)d_out;
  float* out_fy   = out_pred + (size_t)BDIM*NDIM*TTGT*CDIM;

  char* ws = (char*)d_ws;
  size_t off = 0;
  auto alloc = [&](size_t bytes)->void* {
    void* pp = ws + off; off += (bytes + 255) & ~(size_t)255; return pp;
  };
  float* xs    = (float*)alloc((size_t)TSRC*NBATCH*CDIM*4);
  float* h_l0  = (float*)alloc((size_t)NBATCH*HDIM*4);
  float* h_l1  = (float*)alloc((size_t)NBATCH*HDIM*4);
  float* h_d0  = (float*)alloc((size_t)NBATCH*HDIM*4);
  float* h_d1  = (float*)alloc((size_t)NBATCH*HDIM*4);
  float* q     = (float*)alloc((size_t)NBATCH*HDIM*4);
  float* ctx   = (float*)alloc((size_t)NBATCH*HDIM*4);
  float* dec_in= (float*)alloc((size_t)NBATCH*CDIM*4);
  __hip_bfloat16* en_out = (__hip_bfloat16*)alloc((size_t)TSRC*NBATCH*HDIM*2);
  __hip_bfloat16* p_attn = (__hip_bfloat16*)alloc((size_t)TSRC*NBATCH*HDIM*2);

  // passthrough output: flow_y
  hipMemcpyAsync(out_fy, flow_y, (size_t)BDIM*NDIM*TTGT*CDIM*4,
                 hipMemcpyDeviceToDevice, stream);
  pack_xs_kernel<<<(TSRC*NBATCH*CDIM + 255)/256, 256, 0, stream>>>(flow_x, xs);
  hipMemsetAsync(h_l0, 0, (size_t)NBATCH*HDIM*4, stream);
  hipMemsetAsync(h_l1, 0, (size_t)NBATCH*HDIM*4, stream);

  // encoder: lockstep layer0 -> layer1 per step; layer1 h stored to en_out (bf16)
  for (int t=0;t<TSRC;t++){
    gru_step_kernel<<<NBATCH/GRU_ROWS, 256, 0, stream>>>(
      xs + (size_t)t*NBATCH*CDIM, CDIM, nullptr, 0, h_l0,
      enc_w_ih0, enc_w_hh, enc_b_ih, enc_b_hh, nullptr);
    gru_step_kernel<<<NBATCH/GRU_ROWS, 256, 0, stream>>>(
      h_l0, HDIM, nullptr, 0, h_l1,
      enc_w_ih1, enc_w_hh + 3*HDIM*HDIM, enc_b_ih + 3*HDIM, enc_b_hh + 3*HDIM,
      en_out + (size_t)t*NBATCH*HDIM);
  }
  // hidden = tanh(hT @ enc_hid_w.T + b)
  gemm128_kernel<float,float,1><<<NBATCH/16,256,0,stream>>>(
      h_l0, enc_hid_w, HDIM, 0, enc_hid_b, h_d0, NBATCH);
  gemm128_kernel<float,float,1><<<NBATCH/16,256,0,stream>>>(
      h_l1, enc_hid_w, HDIM, 0, enc_hid_b, h_d1, NBATCH);
  // p = en_out @ attn_w[:,H:].T + attn_b   (decoder-invariant part of energy)
  gemm128_kernel<__hip_bfloat16,__hip_bfloat16,0><<<(TSRC*NBATCH)/16,256,0,stream>>>(
      en_out, attn_w, 2*HDIM, HDIM, attn_b, p_attn, TSRC*NBATCH);

  // decoder
  for (int t=0;t<TTGT;t++){
    gemm128_kernel<float,float,0><<<NBATCH/16,256,0,stream>>>(
        h_d1, attn_w, 2*HDIM, 0, nullptr, q, NBATCH);
    attn_kernel<<<NBATCH, 64, 0, stream>>>(p_attn, q, en_out, v_w, ctx);
    const float* din_cur = (t==0) ? (xs + (size_t)(TSRC-1)*NBATCH*CDIM) : dec_in;
    gru_step_kernel<<<NBATCH/GRU_ROWS,256,0,stream>>>(
        din_cur, CDIM, ctx, HDIM, h_d0,
        dec_w_ih0, dec_w_hh, dec_b_ih, dec_b_hh, nullptr);
    gru_step_kernel<<<NBATCH/GRU_ROWS,256,0,stream>>>(
        h_d0, HDIM, nullptr, 0, h_d1,
        dec_w_ih1, dec_w_hh + 3*HDIM*HDIM, dec_b_ih + 3*HDIM, dec_b_hh + 3*HDIM,
        nullptr);
    fc_kernel<<<NBATCH/256,256,0,stream>>>(h_d1, din_cur, fc_w, fc_b,
                                           out_pred, dec_in, t);
  }
}

// Round 2
// 2578.784 us; speedup vs baseline: 3.6311x; 3.6311x over previous
//
#include <hip/hip_runtime.h>
#include <hip/hip_bf16.h>
#include <math.h>

#define NB   8192
#define TSRC 48
#define TTGT 12
#define HD   128

typedef float  f32x4  __attribute__((ext_vector_type(4)));
typedef short  bf16x8 __attribute__((ext_vector_type(8)));

__device__ __forceinline__ float bf2f(unsigned short u){
  return __uint_as_float(((unsigned)u) << 16);
}
__device__ __forceinline__ unsigned short f2bf(float f){
  unsigned u = __float_as_uint(f);
  u += 0x7fffu + ((u >> 16) & 1u);
  return (unsigned short)(u >> 16);
}
__device__ __forceinline__ float sigm(float x){ return 1.0f/(1.0f+__expf(-x)); }
__device__ __forceinline__ float tanhfast(float x){
  float a = fminf(fabsf(x), 15.0f);
  float e = __expf(2.0f*a);
  float r = 1.0f - 2.0f/(e+1.0f);
  return copysignf(r, x);
}
__device__ __forceinline__ f32x4 mfma16(bf16x8 a, bf16x8 b, f32x4 c){
  return __builtin_amdgcn_mfma_f32_16x16x32_bf16(a, b, c, 0, 0, 0);
}

// ---------------- fused GRU layer: gates = [h | x] @ Wcat^T, gating, h update.
// Block = 512 thr = 8 waves, BM=32 rows. Wave (wr,wc): rows wr*16.., cols
// {r,z,n}-triple at 32*wc.. (ct pair per gate). n-gate acc split at k=128 so
// i_n and h_n stay separate (GRU semantics). S1MODE: 1 = LDS (swizzled),
// 2 = on-the-fly bf16 of 3 fp32 cols (padded to 32 with zeros).
template<int K1, int K2, int S1MODE, bool YLDS>
__device__ __forceinline__ void gru_layer(
    int row0,
    const unsigned short* __restrict__ segH,
    const short* s1_lds, const float* __restrict__ x3,
    const unsigned short* __restrict__ seg2,
    const unsigned short* __restrict__ W,
    const float* __restrict__ b_ih, const float* __restrict__ b_hh,
    float* __restrict__ hf, unsigned short* __restrict__ hbf_out,
    short* y_lds)
{
  constexpr int K = 128 + K1 + K2;
  constexpr int NKS = K / 32;
  const int tid  = threadIdx.x;
  const int lane = tid & 63;
  const int wv   = tid >> 6;
  const int wr   = wv >> 2, wc = wv & 3;
  const int l15  = lane & 15;
  const int koff = (lane >> 4) * 8;
  const int arow = row0 + wr*16 + l15;

  const f32x4 zero = {0.f,0.f,0.f,0.f};
  f32x4 aR[2], aZ[2], aNh[2], aNi[2];
  #pragma unroll
  for (int c=0;c<2;c++){ aR[c]=zero; aZ[c]=zero; aNh[c]=zero; aNi[c]=zero; }

  const unsigned short* Wb[3][2];
  #pragma unroll
  for (int g=0;g<3;g++){
    #pragma unroll
    for (int c=0;c<2;c++)
      Wb[g][c] = W + (size_t)(g*128 + wc*32 + c*16 + l15) * K;
  }

  #pragma unroll
  for (int ks=0; ks<NKS; ks++){
    const int kb = ks*32;
    const int kk = kb + koff;
    bf16x8 a;
    if (kb < 128){
      a = *(const bf16x8*)(segH + (size_t)arow*128 + kk);
    } else if (kb < 128 + K1){
      if (S1MODE == 1){
        const int lr = arow - row0;
        const int el = (kk - 128) ^ ((lr & 7) << 3);
        a = *(const bf16x8*)(s1_lds + lr*128 + el);
      } else {
        #pragma unroll
        for (int i=0;i<8;i++) a[i] = 0;
        if (koff == 0){
          const float* s = x3 + (size_t)arow*3;
          a[0] = (short)f2bf(s[0]);
          a[1] = (short)f2bf(s[1]);
          a[2] = (short)f2bf(s[2]);
        }
      }
    } else {
      a = *(const bf16x8*)(seg2 + (size_t)arow*K2 + (kk - 128 - K1));
    }
    #pragma unroll
    for (int c=0;c<2;c++){
      bf16x8 b0 = *(const bf16x8*)(Wb[0][c] + kk);
      aR[c] = mfma16(a, b0, aR[c]);
      bf16x8 b1 = *(const bf16x8*)(Wb[1][c] + kk);
      aZ[c] = mfma16(a, b1, aZ[c]);
      bf16x8 b2 = *(const bf16x8*)(Wb[2][c] + kk);
      if (kb < 128) aNh[c] = mfma16(a, b2, aNh[c]);
      else          aNi[c] = mfma16(a, b2, aNi[c]);
    }
  }
  __syncthreads();   // all A-reads done before in-place h writes
  #pragma unroll
  for (int c=0;c<2;c++){
    const int j = wc*32 + c*16 + l15;
    const float bR  = b_ih[j]       + b_hh[j];
    const float bZ  = b_ih[128 + j] + b_hh[128 + j];
    const float bNi = b_ih[256 + j];
    const float bNh = b_hh[256 + j];
    #pragma unroll
    for (int r=0;r<4;r++){
      const int m = row0 + wr*16 + (lane>>4)*4 + r;
      float rg = sigm(aR[c][r] + bR);
      float zg = sigm(aZ[c][r] + bZ);
      float ng = tanhfast(aNi[c][r] + bNi + rg*(aNh[c][r] + bNh));
      float ho = hf[(size_t)m*HD + j];
      float hn = (1.0f - zg)*ng + zg*ho;
      hf[(size_t)m*HD + j] = hn;
      unsigned short hb = f2bf(hn);
      hbf_out[(size_t)m*HD + j] = hb;
      if (YLDS){
        const int lr = m - row0;
        y_lds[lr*128 + (j ^ ((lr & 7) << 3))] = (short)hb;
      }
    }
  }
}

// -------- encoder: layer0 + layer1 fused per timestep
__global__ __launch_bounds__(512) void enc_step_kernel(
  const unsigned short* __restrict__ h0in, unsigned short* __restrict__ h0out,
  const unsigned short* __restrict__ h1in, unsigned short* __restrict__ h1out,
  const float* __restrict__ x3,
  const unsigned short* __restrict__ Wc0, const unsigned short* __restrict__ Wc1,
  const float* __restrict__ bih0, const float* __restrict__ bhh0,
  const float* __restrict__ bih1, const float* __restrict__ bhh1,
  float* __restrict__ h0f, float* __restrict__ h1f)
{
  __shared__ short ybuf[32*128];
  const int row0 = blockIdx.x * 32;
  gru_layer<32,0,2,true>(row0, h0in, nullptr, x3, nullptr, Wc0, bih0, bhh0, h0f, h0out, ybuf);
  __syncthreads();
  gru_layer<128,0,1,false>(row0, h1in, ybuf, nullptr, nullptr, Wc1, bih1, bhh1, h1f, h1out, nullptr);
}

// -------- decoder megastep: d0 + d1 + q_{t+1} + fc fused
__global__ __launch_bounds__(512) void dec_step_kernel(
  unsigned short* __restrict__ hbf0, unsigned short* __restrict__ hbf1,
  float* __restrict__ din, const unsigned short* __restrict__ ctxbf,
  const unsigned short* __restrict__ Wd0, const unsigned short* __restrict__ Wd1,
  const float* __restrict__ bih0, const float* __restrict__ bhh0,
  const float* __restrict__ bih1, const float* __restrict__ bhh1,
  float* __restrict__ h0f, float* __restrict__ h1f,
  const unsigned short* __restrict__ Wq, float* __restrict__ q,
  const float* __restrict__ fc_w, const float* __restrict__ fc_b,
  float* __restrict__ pred, int t)
{
  __shared__ short ybuf[32*128];
  __shared__ short h1buf[32*128];
  const int row0 = blockIdx.x * 32;
  gru_layer<32,128,2,true>(row0, hbf0, nullptr, din, ctxbf, Wd0, bih0, bhh0, h0f, hbf0, ybuf);
  __syncthreads();
  gru_layer<128,0,1,true>(row0, hbf1, ybuf, nullptr, nullptr, Wd1, bih1, bhh1, h1f, hbf1, h1buf);
  __syncthreads();
  // ---- q_{t+1} = h1_new @ Wq^T (MFMA from swizzled LDS)
  {
    const int tid2 = threadIdx.x, lane = tid2 & 63;
    const int wv = tid2 >> 6, wr = wv >> 2, wc = wv & 3;
    const int l15 = lane & 15, koff = (lane>>4)*8;
    const int lr = wr*16 + l15;
    const f32x4 zero = {0.f,0.f,0.f,0.f};
    f32x4 qa[2]; qa[0]=zero; qa[1]=zero;
    #pragma unroll
    for (int ks=0; ks<4; ks++){
      const int kk = ks*32 + koff;
      bf16x8 a = *(const bf16x8*)(h1buf + lr*128 + (kk ^ ((lr&7)<<3)));
      #pragma unroll
      for (int c=0;c<2;c++){
        const unsigned short* wp = Wq + (size_t)((wc*2 + c)*16 + l15)*128;
        bf16x8 b = *(const bf16x8*)(wp + kk);
        qa[c] = mfma16(a, b, qa[c]);
      }
    }
    #pragma unroll
    for (int c=0;c<2;c++){
      const int j = (wc*2 + c)*16 + l15;
      #pragma unroll
      for (int r=0;r<4;r++){
        const int m = row0 + wr*16 + (lane>>4)*4 + r;
        q[(size_t)m*128 + j] = qa[c][r];
      }
    }
  }
  // ---- fc: out = [h1,h1,din]@fc_w^T + fc_b ; writes pred + next din
  const int tid = threadIdx.x;
  if (tid < 256){
    const int nb_l = tid >> 3, p8 = tid & 7;
    const int nb = row0 + nb_l;
    float o0=0.f, o1=0.f, o2=0.f;
    #pragma unroll
    for (int u=0; u<16; u++){
      const int jj = p8*16 + u;
      float hv = bf2f((unsigned short)h1buf[nb_l*128 + (jj ^ ((nb_l&7)<<3))]);
      o0 += (fc_w[jj]       + fc_w[128 + jj])       * hv;
      o1 += (fc_w[259 + jj] + fc_w[259 + 128 + jj]) * hv;
      o2 += (fc_w[518 + jj] + fc_w[518 + 128 + jj]) * hv;
    }
    #pragma unroll
    for (int off=1; off<8; off<<=1){
      o0 += __shfl_xor(o0, off);
      o1 += __shfl_xor(o1, off);
      o2 += __shfl_xor(o2, off);
    }
    if (p8 == 0){
      float d0 = din[nb*3], d1 = din[nb*3+1], d2 = din[nb*3+2];
      o0 += fc_b[0] + fc_w[256]*d0     + fc_w[257]*d1     + fc_w[258]*d2;
      o1 += fc_b[1] + fc_w[259+256]*d0 + fc_w[259+257]*d1 + fc_w[259+258]*d2;
      o2 += fc_b[2] + fc_w[518+256]*d0 + fc_w[518+257]*d1 + fc_w[518+258]*d2;
      const int n = nb >> 6, b = nb & 63;
      float* pr = pred + ((size_t)(b*128 + n)*TTGT + t)*3;
      pr[0]=o0; pr[1]=o1; pr[2]=o2;
      din[nb*3]=o0; din[nb*3+1]=o1; din[nb*3+2]=o2;
    }
  }
}

// -------- generic [M,128]x[128,128] bf16 MFMA GEMM (bias/tanh/f32/bf16 out)
template<bool BIAS, bool TANH, bool OF32, bool OBF>
__global__ __launch_bounds__(512) void gemm_h128_kernel(
  const unsigned short* __restrict__ A, const unsigned short* __restrict__ W,
  const float* __restrict__ bias, float* __restrict__ of,
  unsigned short* __restrict__ ob)
{
  const int row0 = blockIdx.x * 16;
  const int tid = threadIdx.x, lane = tid & 63, wv = tid >> 6;
  const int l15 = lane & 15, koff = (lane>>4)*8;
  const size_t arow = (size_t)row0 + l15;
  f32x4 acc = {0.f,0.f,0.f,0.f};
  const unsigned short* wp = W + (size_t)(wv*16 + l15)*128;
  #pragma unroll
  for (int ks=0; ks<4; ks++){
    const int kk = ks*32 + koff;
    bf16x8 a = *(const bf16x8*)(A + arow*128 + kk);
    bf16x8 b = *(const bf16x8*)(wp + kk);
    acc = mfma16(a, b, acc);
  }
  const int j = wv*16 + l15;
  const float bb = BIAS ? bias[j] : 0.0f;
  #pragma unroll
  for (int r=0;r<4;r++){
    const size_t m = (size_t)row0 + (lane>>4)*4 + r;
    float v = acc[r] + bb;
    if (TANH) v = tanhfast(v);
    if (OF32) of[m*128 + j] = v;
    if (OBF)  ob[m*128 + j] = f2bf(v);
  }
}

// -------- attention scores: wave per (t,nb); s = sum_j v_j*tanh(p+q)
__global__ __launch_bounds__(512) void scores_kernel(
  const unsigned short* __restrict__ p, const float* __restrict__ q,
  const float* __restrict__ vw, float* __restrict__ S)
{
  const int id = blockIdx.x*8 + (threadIdx.x >> 6);
  const int lane = threadIdx.x & 63;
  const int nb = id & (NB-1);
  const unsigned pu = *(const unsigned*)(p + (size_t)id*128 + lane*2);
  const float2 q2 = *(const float2*)(q + (size_t)nb*128 + lane*2);
  const float2 vv = *(const float2*)(vw + lane*2);
  float s = vv.x * tanhfast(bf2f((unsigned short)(pu & 0xffffu)) + q2.x)
          + vv.y * tanhfast(bf2f((unsigned short)(pu >> 16))    + q2.y);
  #pragma unroll
  for (int off=32; off>=1; off>>=1) s += __shfl_xor(s, off);
  if (lane == 0) S[id] = s;
}

// -------- softmax over t + context accumulation (32 nb per block)
__global__ __launch_bounds__(256) void attn2_kernel(
  const float* __restrict__ S, const unsigned short* __restrict__ en,
  unsigned short* __restrict__ ctxbf)
{
  __shared__ float aw[TSRC][32];
  const int nb0 = blockIdx.x*32;
  const int tid = threadIdx.x;
  if (tid < 32){
    const int nb = nb0 + tid;
    float sv[TSRC];
    float mx = -1e30f;
    #pragma unroll
    for (int t=0;t<TSRC;t++){ sv[t] = S[(size_t)t*NB + nb]; mx = fmaxf(mx, sv[t]); }
    float den = 0.f;
    #pragma unroll
    for (int t=0;t<TSRC;t++){ float e = __expf(sv[t]-mx); sv[t]=e; den += e; }
    float rd = 1.0f/den;
    #pragma unroll
    for (int t=0;t<TSRC;t++) aw[t][tid] = sv[t]*rd;
  }
  __syncthreads();
  const int nb_l = tid >> 3, j16 = (tid & 7)*16;
  const int nb = nb0 + nb_l;
  float acc[16];
  #pragma unroll
  for (int i=0;i<16;i++) acc[i]=0.f;
  for (int t=0;t<TSRC;t++){
    const float a = aw[t][nb_l];
    const unsigned short* er = en + ((size_t)t*NB + nb)*128 + j16;
    const uint4* e4 = (const uint4*)er;
    uint4 ua = e4[0], ub = e4[1];
    unsigned w[8] = {ua.x,ua.y,ua.z,ua.w, ub.x,ub.y,ub.z,ub.w};
    #pragma unroll
    for (int i=0;i<8;i++){
      acc[2*i]   += a*bf2f((unsigned short)(w[i] & 0xffffu));
      acc[2*i+1] += a*bf2f((unsigned short)(w[i] >> 16));
    }
  }
  unsigned short* cp = ctxbf + (size_t)nb*128 + j16;
  #pragma unroll
  for (int i=0;i<16;i++) cp[i] = f2bf(acc[i]);
}

// -------- input pack: xs3[t][nb][3] + initial dec_in
__global__ __launch_bounds__(256) void pack_kernel(
  const float* __restrict__ fx, float* __restrict__ xs3,
  float* __restrict__ din)
{
  int idx = blockIdx.x*256 + threadIdx.x;
  if (idx >= TSRC*NB) return;
  int nb = idx & (NB-1), t = idx >> 13;
  int n = nb >> 6, b = nb & 63;
  const float* s = fx + (((size_t)(b*128) + n)*TSRC + t)*3;
  float x0=s[0], x1=s[1], x2=s[2];
  float* d = xs3 + (size_t)idx*3;
  d[0]=x0; d[1]=x1; d[2]=x2;
  if (t == TSRC-1){ din[nb*3]=x0; din[nb*3+1]=x1; din[nb*3+2]=x2; }
}

// -------- build all bf16 weight concats
__global__ __launch_bounds__(256) void build_kernel(
  const float* __restrict__ e_ih0, const float* __restrict__ e_ih1,
  const float* __restrict__ e_hh,
  const float* __restrict__ d_ih0, const float* __restrict__ d_ih1,
  const float* __restrict__ d_hh,
  const float* __restrict__ attn_w, const float* __restrict__ ehw_f,
  unsigned short* __restrict__ Wc_e0, unsigned short* __restrict__ Wc_e1,
  unsigned short* __restrict__ Wc_d0, unsigned short* __restrict__ Wc_d1,
  unsigned short* __restrict__ Wq, unsigned short* __restrict__ Wp,
  unsigned short* __restrict__ Ehw)
{
  int idx = blockIdx.x*256 + threadIdx.x;
  if (idx >= 417792) return;
  if (idx < 61440){
    int j = idx/160, k = idx%160;
    float v = (k<128) ? e_hh[(size_t)j*128 + k]
            : (k<131) ? e_ih0[j*3 + (k-128)] : 0.0f;
    Wc_e0[idx] = f2bf(v);
  } else if (idx < 159744){
    int i = idx - 61440; int j = i/256, k = i%256;
    float v = (k<128) ? e_hh[(size_t)(384 + j)*128 + k]
                      : e_ih1[(size_t)j*128 + (k-128)];
    Wc_e1[i] = f2bf(v);
  } else if (idx < 270336){
    int i = idx - 159744; int j = i/288, k = i%288;
    float v = (k<128) ? d_hh[(size_t)j*128 + k]
            : (k<131) ? d_ih0[(size_t)j*131 + (k-128)]
            : (k<160) ? 0.0f
                      : d_ih0[(size_t)j*131 + 3 + (k-160)];
    Wc_d0[i] = f2bf(v);
  } else if (idx < 368640){
    int i = idx - 270336; int j = i/256, k = i%256;
    float v = (k<128) ? d_hh[(size_t)(384 + j)*128 + k]
                      : d_ih1[(size_t)j*128 + (k-128)];
    Wc_d1[i] = f2bf(v);
  } else if (idx < 385024){
    int i = idx - 368640; int j = i/128, k = i%128;
    Wq[i] = f2bf(attn_w[(size_t)j*256 + k]);
  } else if (idx < 401408){
    int i = idx - 385024; int j = i/128, k = i%128;
    Wp[i] = f2bf(attn_w[(size_t)j*256 + 128 + k]);
  } else {
    int i = idx - 401408;
    Ehw[i] = f2bf(ehw_f[i]);
  }
}

extern "C" void kernel_launch(void* const* d_in, const int* in_sizes, int n_in,
                              void* d_out, int out_size, void* d_ws, size_t ws_size,
                              hipStream_t stream)
{
  const float* flow_x   = (const float*)d_in[0];
  const float* flow_y   = (const float*)d_in[1];
  const float* enc_w_ih0= (const float*)d_in[2];
  const float* enc_w_ih1= (const float*)d_in[3];
  const float* enc_w_hh = (const float*)d_in[4];
  const float* enc_b_ih = (const float*)d_in[5];
  const float* enc_b_hh = (const float*)d_in[6];
  const float* enc_hid_w= (const float*)d_in[7];
  const float* enc_hid_b= (const float*)d_in[8];
  const float* dec_w_ih0= (const float*)d_in[9];
  const float* dec_w_ih1= (const float*)d_in[10];
  const float* dec_w_hh = (const float*)d_in[11];
  const float* dec_b_ih = (const float*)d_in[12];
  const float* dec_b_hh = (const float*)d_in[13];
  const float* attn_w   = (const float*)d_in[14];
  const float* attn_b   = (const float*)d_in[15];
  const float* v_w      = (const float*)d_in[16];
  const float* fc_w     = (const float*)d_in[17];
  const float* fc_b     = (const float*)d_in[18];

  float* out_pred = (float*)d_out;
  float* out_fy   = out_pred + (size_t)64*128*TTGT*3;

  char* ws = (char*)d_ws;
  size_t off = 0;
  auto alloc = [&](size_t bytes)->void* {
    void* pp = ws + off; off += (bytes + 255) & ~(size_t)255; return pp;
  };
  float*          xs3    = (float*)alloc((size_t)TSRC*NB*3*4);
  float*          din    = (float*)alloc((size_t)NB*3*4);
  unsigned short* zbuf   = (unsigned short*)alloc((size_t)NB*HD*2);
  unsigned short* hbf0   = (unsigned short*)alloc((size_t)NB*HD*2);
  unsigned short* en_out = (unsigned short*)alloc((size_t)TSRC*NB*HD*2);
  unsigned short* p_attn = (unsigned short*)alloc((size_t)TSRC*NB*HD*2);
  float*          Sbuf   = (float*)alloc((size_t)TSRC*NB*4);
  float*          q      = (float*)alloc((size_t)NB*HD*4);
  unsigned short* ctxbf  = (unsigned short*)alloc((size_t)NB*HD*2);
  float*          h0f    = (float*)alloc((size_t)NB*HD*4);
  float*          h1f    = (float*)alloc((size_t)NB*HD*4);
  float*          h0fd   = (float*)alloc((size_t)NB*HD*4);
  float*          h1fd   = (float*)alloc((size_t)NB*HD*4);
  unsigned short* hbf_d0 = (unsigned short*)alloc((size_t)NB*HD*2);
  unsigned short* hbf_d1 = (unsigned short*)alloc((size_t)NB*HD*2);
  unsigned short* Wc_e0  = (unsigned short*)alloc((size_t)384*160*2);
  unsigned short* Wc_e1  = (unsigned short*)alloc((size_t)384*256*2);
  unsigned short* Wc_d0  = (unsigned short*)alloc((size_t)384*288*2);
  unsigned short* Wc_d1  = (unsigned short*)alloc((size_t)384*256*2);
  unsigned short* attnWq = (unsigned short*)alloc((size_t)128*128*2);
  unsigned short* attnWp = (unsigned short*)alloc((size_t)128*128*2);
  unsigned short* Ehw    = (unsigned short*)alloc((size_t)128*128*2);

  hipMemcpyAsync(out_fy, flow_y, (size_t)64*128*TTGT*3*4,
                 hipMemcpyDeviceToDevice, stream);
  build_kernel<<<1632, 256, 0, stream>>>(
      enc_w_ih0, enc_w_ih1, enc_w_hh, dec_w_ih0, dec_w_ih1, dec_w_hh,
      attn_w, enc_hid_w, Wc_e0, Wc_e1, Wc_d0, Wc_d1, attnWq, attnWp, Ehw);
  pack_kernel<<<1536, 256, 0, stream>>>(flow_x, xs3, din);
  hipMemsetAsync(h0f, 0, (size_t)NB*HD*4, stream);
  hipMemsetAsync(h1f, 0, (size_t)NB*HD*4, stream);
  hipMemsetAsync(zbuf, 0, (size_t)NB*HD*2, stream);

  // ---- encoder
  for (int t=0; t<TSRC; t++){
    const unsigned short* h0in = (t==0) ? zbuf : hbf0;
    const unsigned short* h1in = (t==0) ? zbuf : en_out + (size_t)(t-1)*NB*HD;
    enc_step_kernel<<<NB/32, 512, 0, stream>>>(
        h0in, hbf0, h1in, en_out + (size_t)t*NB*HD,
        xs3 + (size_t)t*NB*3, Wc_e0, Wc_e1,
        enc_b_ih, enc_b_hh, enc_b_ih + 384, enc_b_hh + 384, h0f, h1f);
  }
  // ---- hidden init: h_d = tanh(hT @ enc_hid_w^T + b)
  gemm_h128_kernel<true,true,true,true><<<NB/16, 512, 0, stream>>>(
      hbf0, Ehw, enc_hid_b, h0fd, hbf_d0);
  gemm_h128_kernel<true,true,true,true><<<NB/16, 512, 0, stream>>>(
      en_out + (size_t)(TSRC-1)*NB*HD, Ehw, enc_hid_b, h1fd, hbf_d1);
  // ---- p = en_out @ Wp^T + attn_b (decoder-invariant)
  gemm_h128_kernel<true,false,false,true><<<(TSRC*NB)/16, 512, 0, stream>>>(
      en_out, attnWp, attn_b, nullptr, p_attn);
  // ---- q0 = hbf_d1 @ Wq^T
  gemm_h128_kernel<false,false,true,false><<<NB/16, 512, 0, stream>>>(
      hbf_d1, attnWq, nullptr, q, nullptr);

  // ---- decoder
  for (int t=0; t<TTGT; t++){
    scores_kernel<<<(TSRC*NB)/8, 512, 0, stream>>>(p_attn, q, v_w, Sbuf);
    attn2_kernel<<<NB/32, 256, 0, stream>>>(Sbuf, en_out, ctxbf);
    dec_step_kernel<<<NB/32, 512, 0, stream>>>(
        hbf_d0, hbf_d1, din, ctxbf, Wc_d0, Wc_d1,
        dec_b_ih, dec_b_hh, dec_b_ih + 384, dec_b_hh + 384,
        h0fd, h1fd, attnWq, q, fc_w, fc_b, out_pred, t);
  }
}